// Round 3
// baseline (155.447 us; speedup 1.0000x reference)
//
#include <hip/hip_runtime.h>

// LoRA: out = x @ (A@B) * 1.0, computed as (x@A)@B.
// x: [M=16384, K=4096] f32, A: [K, 16] f32, B: [16, N=4096] f32.
constexpr int RANK = 16;
constexpr int K = 4096;
constexpr int N = 4096;
constexpr int M = 4 * 4096;
constexpr int KC = 512;       // K-chunk staged in LDS (16 x 512 floats = 32KB)
constexpr int NCHUNK = K / KC;
constexpr int ROWS2 = 32;     // rows per block in kernel 2

// ---------------- Kernel 1: T = x @ A ----------------
// Block = 256 threads (4 waves), 16 rows (4 per wave). A is staged TRANSPOSED
// in LDS: AsT[j][k] (j=0..15, k=0..511). Lane l owns k-quad 4l..4l+3:
//   - x loads are float4 (16B/lane, perfectly coalesced, 64 instrs/thread)
//   - A fragment: AsT[j][kb+4l] as float4 -> consecutive lanes hit
//     consecutive 16B slots -> conflict-free 8-cycle wave64 ds_read_b128.
// Staging: coalesced global float4 reads of A (row-major), 4-scalar ds_write
// transpose scatter (tiny volume; 4-way write conflict is negligible).
// Epilogue: recursive-halving reduce-scatter (63 shuffles) -> lane i holds
// element i of the wave's 4x16 tile -> one coalesced 256B store per wave.

__global__ __launch_bounds__(256) void lora_xa(const float* __restrict__ x,
                                               const float* __restrict__ A,
                                               float* __restrict__ T) {
  const int lane = threadIdx.x & 63;
  const int tid = threadIdx.x;
  const int wave = tid >> 6;
  const int r0 = blockIdx.x * 16 + wave * 4;  // this wave's 4 rows

  __shared__ float AsT[RANK][KC];  // 32 KB, transposed A chunk

  const float4* __restrict__ A4 = reinterpret_cast<const float4*>(A);
  const float4* __restrict__ x4 = reinterpret_cast<const float4*>(x);

  float vals[64];
#pragma unroll
  for (int i = 0; i < 64; ++i) vals[i] = 0.0f;

  for (int c = 0; c < NCHUNK; ++c) {
    __syncthreads();  // protect LDS from previous chunk's readers
    // ---- stage chunk c (transposed): 2048 float4, 8 per thread ----
#pragma unroll
    for (int q = 0; q < 8; ++q) {
      const int n = q * 256 + tid;   // n = k*4 + s
      const int k = n >> 2;          // local row 0..511
      const int s = n & 3;           // float4 slot within row (cols 4s..4s+3)
      const float4 v = A4[(size_t)c * 2048 + n];  // coalesced
      AsT[4 * s + 0][k] = v.x;
      AsT[4 * s + 1][k] = v.y;
      AsT[4 * s + 2][k] = v.z;
      AsT[4 * s + 3][k] = v.w;
    }
    __syncthreads();

    // ---- compute: 2 k-blocks of 256 (k-quad per lane) ----
#pragma unroll
    for (int kbi = 0; kbi < KC / 256; ++kbi) {
      const int klq = kbi * 64 + lane;              // local k-quad index
      const size_t kgq = (size_t)c * (KC / 4) + klq;  // global k-quad index

      float4 xv[4];
#pragma unroll
      for (int r = 0; r < 4; ++r)
        xv[r] = x4[(size_t)(r0 + r) * (K / 4) + kgq];

#pragma unroll
      for (int jg = 0; jg < 4; ++jg) {
        float4 a[4];
#pragma unroll
        for (int jj = 0; jj < 4; ++jj)
          a[jj] = *reinterpret_cast<const float4*>(&AsT[4 * jg + jj][klq * 4]);
#pragma unroll
        for (int r = 0; r < 4; ++r) {
#pragma unroll
          for (int jj = 0; jj < 4; ++jj) {
            float acc = vals[r * 16 + 4 * jg + jj];
            acc = fmaf(xv[r].x, a[jj].x, acc);
            acc = fmaf(xv[r].y, a[jj].y, acc);
            acc = fmaf(xv[r].z, a[jj].z, acc);
            acc = fmaf(xv[r].w, a[jj].w, acc);
            vals[r * 16 + 4 * jg + jj] = acc;
          }
        }
      }
    }
  }

  // Recursive-halving reduce-scatter across the 64 lanes.
  // After all steps, lane i holds the fully-summed element i (r=i>>4, j=i&15).
#define RSTEP(HALF)                                            \
  {                                                            \
    const bool hi = (lane & (HALF)) != 0;                      \
    _Pragma("unroll")                                          \
    for (int i = 0; i < (HALF); ++i) {                         \
      const float send = hi ? vals[i] : vals[i + (HALF)];      \
      const float keep = hi ? vals[i + (HALF)] : vals[i];      \
      vals[i] = keep + __shfl_xor(send, (HALF), 64);           \
    }                                                          \
  }
  RSTEP(32)
  RSTEP(16)
  RSTEP(8)
  RSTEP(4)
  RSTEP(2)
  RSTEP(1)
#undef RSTEP

  T[(size_t)(r0 + (lane >> 4)) * RANK + (lane & 15)] = vals[0];
}

// ---------------- Kernel 2: out = T @ B ----------------
// Each thread holds B[0..15][n0..n0+3] in 64 VGPRs (loaded once), then loops
// ROWS2 rows. T reads are block-uniform (scalar path); stores are coalesced
// float4 at 16B/lane. Near the 256-MiB write roofline already.
__global__ __launch_bounds__(256) void lora_tb(const float* __restrict__ T,
                                               const float* __restrict__ B,
                                               float* __restrict__ out) {
  const int n0 = blockIdx.x * 1024 + threadIdx.x * 4;
  const int r0 = blockIdx.y * ROWS2;

  const float4* __restrict__ B4 = reinterpret_cast<const float4*>(B);
  float4* __restrict__ out4 = reinterpret_cast<float4*>(out);

  float4 b[16];
#pragma unroll
  for (int j = 0; j < RANK; ++j) b[j] = B4[((size_t)j * N + n0) >> 2];

  for (int r = 0; r < ROWS2; ++r) {
    const float* __restrict__ t = T + (size_t)(r0 + r) * RANK;
    float4 acc;
    acc.x = acc.y = acc.z = acc.w = 0.0f;
#pragma unroll
    for (int j = 0; j < RANK; ++j) {
      const float ts = t[j];
      acc.x = fmaf(ts, b[j].x, acc.x);
      acc.y = fmaf(ts, b[j].y, acc.y);
      acc.z = fmaf(ts, b[j].z, acc.z);
      acc.w = fmaf(ts, b[j].w, acc.w);
    }
    out4[((size_t)(r0 + r) * N + n0) >> 2] = acc;
  }
}

extern "C" void kernel_launch(void* const* d_in, const int* in_sizes, int n_in,
                              void* d_out, int out_size, void* d_ws, size_t ws_size,
                              hipStream_t stream) {
  const float* x = (const float*)d_in[0];   // [M, K]
  const float* A = (const float*)d_in[1];   // [K, RANK]
  const float* B = (const float*)d_in[2];   // [RANK, N]
  float* out = (float*)d_out;               // [M, N]
  float* T = (float*)d_ws;                  // [M, RANK] scratch (1 MiB)

  // Kernel 1: 16 rows per block (4 waves x 4 rows) -> 1024 blocks.
  lora_xa<<<M / 16, 256, 0, stream>>>(x, A, T);

  // Kernel 2: grid (N/1024, M/ROWS2).
  lora_tb<<<dim3(N / 1024, M / ROWS2), 256, 0, stream>>>(T, B, out);
}